// Round 5
// baseline (1773.761 us; speedup 1.0000x reference)
//
#include <hip/hip_runtime.h>
#include <stdint.h>

typedef unsigned short u16;
typedef short s16x8 __attribute__((ext_vector_type(8)));
typedef float f32x4 __attribute__((ext_vector_type(4)));

#define HW 65536
#define CD 192
#define C3 576
#define QB ((size_t)HW * C3)

static __device__ __forceinline__ float bf2f(u16 u) {
    return __uint_as_float(((uint32_t)u) << 16);
}
static __device__ __forceinline__ u16 f2bf(float f) {
    uint32_t x = __float_as_uint(f);
    return (u16)((x + 0x7fffu + ((x >> 16) & 1u)) >> 16);  // RNE
}

// ---------------------------------------------------------------------------
// convert fp32 -> bf16 (qkv_w, 576*192 elements)
// ---------------------------------------------------------------------------
__launch_bounds__(256)
__global__ void k_convert(const float* __restrict__ in, u16* __restrict__ out, int n4)
{
    int i = blockIdx.x * 256 + threadIdx.x;
    if (i >= n4) return;
    float4 v = ((const float4*)in)[i];
    ushort4 o;
    o.x = f2bf(v.x); o.y = f2bf(v.y); o.z = f2bf(v.z); o.w = f2bf(v.w);
    ((ushort4*)out)[i] = o;
}

// ---------------------------------------------------------------------------
// K1: QKV gemm (MFMA).  qkvt[p][o] = sum_c qkvw[o][c] * x[b][c][p]
//   A = qkvwb bf16 [576][192]; X staged straight from fp32 x (c-major).
//   BM=192, BN=128, BK=32, 4 waves 2x2, 6x4 acc tiles per wave.
// ---------------------------------------------------------------------------
__launch_bounds__(256, 2)
__global__ void k_qkv(const u16* __restrict__ A, const float* __restrict__ x,
                      u16* __restrict__ O, int b0)
{
    __shared__ __attribute__((aligned(16))) u16 As[192 * 40];
    __shared__ __attribute__((aligned(16))) u16 Xs[128 * 40];
    const int t    = threadIdx.x;
    const int pb   = blockIdx.z;
    const int m0g  = blockIdx.y * 192;
    const int p0   = blockIdx.x * 128;
    const int lane = t & 63, wid = t >> 6;
    const int quad = lane >> 4, l16 = lane & 15;
    const int wm0  = (wid >> 1) * 96, wn0 = (wid & 1) * 64;

    f32x4 acc[6][4];
    #pragma unroll
    for (int i = 0; i < 6; i++)
        #pragma unroll
        for (int j = 0; j < 4; j++) acc[i][j] = f32x4{0.f, 0.f, 0.f, 0.f};

    const float* Xb = x + (size_t)(b0 + pb) * CD * HW;

    for (int kk = 0; kk < 6; kk++) {
        if (kk) __syncthreads();
        #pragma unroll
        for (int i = 0; i < 3; i++) {           // A tile: 192x32
            int s = t + i * 256;
            int m = s >> 2, part = s & 3;
            uint4 v = *(const uint4*)(A + (size_t)(m0g + m) * CD + kk * 32 + part * 8);
            *(uint4*)(&As[m * 40 + part * 8]) = v;
        }
        #pragma unroll
        for (int i = 0; i < 4; i++) {           // X tile: 32 c x 128 p, from fp32
            int s = t + i * 256;
            int c_l = s >> 5, seg = s & 31;
            float4 v = *(const float4*)(Xb + (size_t)(kk * 32 + c_l) * HW + p0 + seg * 4);
            Xs[(seg * 4 + 0) * 40 + c_l] = f2bf(v.x);
            Xs[(seg * 4 + 1) * 40 + c_l] = f2bf(v.y);
            Xs[(seg * 4 + 2) * 40 + c_l] = f2bf(v.z);
            Xs[(seg * 4 + 3) * 40 + c_l] = f2bf(v.w);
        }
        __syncthreads();
        s16x8 af[6], bfr[4];
        #pragma unroll
        for (int i = 0; i < 6; i++)
            af[i] = *(const s16x8*)(&As[(wm0 + i * 16 + l16) * 40 + quad * 8]);
        #pragma unroll
        for (int j = 0; j < 4; j++)
            bfr[j] = *(const s16x8*)(&Xs[(wn0 + j * 16 + l16) * 40 + quad * 8]);
        #pragma unroll
        for (int i = 0; i < 6; i++)
            #pragma unroll
            for (int j = 0; j < 4; j++)
                acc[i][j] = __builtin_amdgcn_mfma_f32_16x16x32_bf16(af[i], bfr[j], acc[i][j], 0, 0, 0);
    }

    u16* Ob = O + QB * pb;
    #pragma unroll
    for (int i = 0; i < 6; i++) {
        const int o = m0g + wm0 + i * 16 + quad * 4;   // rows o..o+3
        #pragma unroll
        for (int j = 0; j < 4; j++) {
            const int p = p0 + wn0 + j * 16 + l16;
            ushort4 v;
            v.x = f2bf(acc[i][j][0]); v.y = f2bf(acc[i][j][1]);
            v.z = f2bf(acc[i][j][2]); v.w = f2bf(acc[i][j][3]);
            *(ushort4*)(Ob + (size_t)p * C3 + o) = v;
        }
    }
}

// ---------------------------------------------------------------------------
// K2: depthwise 3x3, SAME padding, staged: block = (8-wide w chunk, h, pb).
// ---------------------------------------------------------------------------
__launch_bounds__(256)
__global__ void k_dw(const u16* __restrict__ qkv, const float* __restrict__ dww,
                     u16* __restrict__ out)
{
    __shared__ __attribute__((aligned(16))) u16 stage[3 * 10 * 576];
    __shared__ float wts[5184];
    const int t  = threadIdx.x;
    const int pb = blockIdx.z;
    const int h  = blockIdx.y;
    const int w0 = blockIdx.x * 8;

    for (int i = t; i < 5184; i += 256) wts[i] = dww[i];
    const u16* src = qkv + (size_t)pb * QB;
    #pragma unroll
    for (int i = 0; i < 9; i++) {
        int s = t + i * 256;
        if (s < 2160) {
            int c0 = (s % 72) * 8;
            int r = s / 72;
            int wpos = r % 10, hh = r / 10;
            int gh = h + hh - 1, gw = w0 + wpos - 1;
            uint4 v = make_uint4(0, 0, 0, 0);
            if ((unsigned)gh < 256u && (unsigned)gw < 256u)
                v = *(const uint4*)(src + ((size_t)gh * 256 + gw) * C3 + c0);
            *(uint4*)(&stage[(hh * 10 + wpos) * 576 + c0]) = v;
        }
    }
    __syncthreads();

    u16* dst = out + (size_t)pb * QB + ((size_t)h * 256 + w0) * C3;
    for (int ci = 0; ci < 3; ci++) {
        int c = t + ci * 256;
        if (c >= C3) break;
        float w9[9];
        #pragma unroll
        for (int k = 0; k < 9; k++) w9[k] = wts[c * 9 + k];
        float acc8[8] = {0.f, 0.f, 0.f, 0.f, 0.f, 0.f, 0.f, 0.f};
        #pragma unroll
        for (int hh = 0; hh < 3; hh++) {
            float s10[10];
            #pragma unroll
            for (int wp = 0; wp < 10; wp++) s10[wp] = bf2f(stage[(hh * 10 + wp) * 576 + c]);
            #pragma unroll
            for (int wi = 0; wi < 8; wi++)
                acc8[wi] += s10[wi]     * w9[hh * 3]
                          + s10[wi + 1] * w9[hh * 3 + 1]
                          + s10[wi + 2] * w9[hh * 3 + 2];
        }
        #pragma unroll
        for (int wi = 0; wi < 8; wi++) dst[(size_t)wi * C3 + c] = f2bf(acc8[wi]);
    }
}

// ---------------------------------------------------------------------------
// K3: per-channel sum of squares over all p, channels 0..383 (q then k).
// ---------------------------------------------------------------------------
__launch_bounds__(256)
__global__ void k_sumsq(const u16* __restrict__ dwt, float* __restrict__ sums, int b0)
{
    const int t = threadIdx.x;
    const int pb = blockIdx.y, chunk = blockIdx.x;
    const u16* src = dwt + (size_t)pb * QB + (size_t)chunk * 512 * C3;
    float a0 = 0.f, a1 = 0.f;
    for (int r = 0; r < 512; r++) {
        float v0 = bf2f(src[(size_t)r * C3 + t]);
        a0 += v0 * v0;
        if (t < 128) {
            float v1 = bf2f(src[(size_t)r * C3 + 256 + t]);
            a1 += v1 * v1;
        }
    }
    atomicAdd(&sums[(b0 + pb) * 384 + t], a0);
    if (t < 128) atomicAdd(&sums[(b0 + pb) * 384 + 256 + t], a1);
}

// ---------------------------------------------------------------------------
// K4: raw attn dots, staged. block=(256-p chunk, head, pb).
// ---------------------------------------------------------------------------
__launch_bounds__(256)
__global__ void k_attn(const u16* __restrict__ dwt, float* __restrict__ araw, int b0)
{
    __shared__ __attribute__((aligned(16))) u16 qk[256 * 48];
    __shared__ float red[576];
    const int t = threadIdx.x;
    const int pb = blockIdx.z, hh = blockIdx.y, chunk = blockIdx.x;
    const u16* src = dwt + (size_t)pb * QB + (size_t)chunk * 256 * C3;
    const int qcol = hh * 24, kcol = CD + hh * 24;
    #pragma unroll
    for (int i = 0; i < 6; i++) {
        int s = t + i * 256;
        int n = s / 6, part = s % 6;
        int col  = (part < 3) ? (qcol + part * 8) : (kcol + (part - 3) * 8);
        int dstc = (part < 3) ? (part * 8) : (24 + (part - 3) * 8);
        *(uint4*)(&qk[n * 48 + dstc]) = *(const uint4*)(src + (size_t)n * C3 + col);
    }
    for (int i = t; i < 576; i += 256) red[i] = 0.f;
    __syncthreads();
    const int lane = t & 63, wid = t >> 6;
    const int d0 = (lane >> 3) * 3, e0 = (lane & 7) * 3;
    float acc[3][3] = {};
    const u16* base = &qk[wid * 64 * 48];
    for (int n = 0; n < 64; n++) {
        float qv[3], kv[3];
        #pragma unroll
        for (int i = 0; i < 3; i++) qv[i] = bf2f(base[n * 48 + d0 + i]);
        #pragma unroll
        for (int j = 0; j < 3; j++) kv[j] = bf2f(base[n * 48 + 24 + e0 + j]);
        #pragma unroll
        for (int i = 0; i < 3; i++)
            #pragma unroll
            for (int j = 0; j < 3; j++) acc[i][j] += qv[i] * kv[j];
    }
    #pragma unroll
    for (int i = 0; i < 3; i++)
        #pragma unroll
        for (int j = 0; j < 3; j++)
            atomicAdd(&red[(d0 + i) * 24 + (e0 + j)], acc[i][j]);
    __syncthreads();
    float* dst = araw + ((size_t)(b0 + pb) * 8 + hh) * 576;
    for (int i = t; i < 576; i += 256) atomicAdd(&dst[i], red[i]);
}

// ---------------------------------------------------------------------------
// K4b: apply q/k norm scales + temperature, softmax over e.
// ---------------------------------------------------------------------------
__global__ void k_softmax(const float* __restrict__ araw, const float* __restrict__ sums,
                          const float* __restrict__ temp, float* __restrict__ attnS, int b0)
{
    const int b = b0 + blockIdx.y, hh = blockIdx.x, t = threadIdx.x;
    __shared__ float qsc[24], ksc[24];
    if (t < 24) {
        qsc[t] = 1.f / fmaxf(sqrtf(sums[b * 384 + hh * 24 + t]), 1e-12f);
        ksc[t] = 1.f / fmaxf(sqrtf(sums[b * 384 + CD + hh * 24 + t]), 1e-12f);
    }
    __syncthreads();
    if (t < 24) {
        const float tp = temp[hh];
        const float qs = qsc[t];
        const float* row = araw + ((size_t)b * 8 + hh) * 576 + t * 24;
        float v[24], m = -1e30f;
        #pragma unroll
        for (int e = 0; e < 24; e++) { v[e] = row[e] * qs * ksc[e] * tp; m = fmaxf(m, v[e]); }
        float ssum = 0.f;
        #pragma unroll
        for (int e = 0; e < 24; e++) { v[e] = expf(v[e] - m); ssum += v[e]; }
        const float inv = 1.f / ssum;
        float* orow = attnS + ((size_t)b * 8 + hh) * 576 + t * 24;
        #pragma unroll
        for (int e = 0; e < 24; e++) orow[e] = v[e] * inv;
    }
}

// ---------------------------------------------------------------------------
// K4c: Meff[b][o][h*24+e] = sum_d proj_w[o][h*24+d] * attnS[b][h][d][e]
// ---------------------------------------------------------------------------
__launch_bounds__(256)
__global__ void k_meff(const float* __restrict__ attnS, const float* __restrict__ projw,
                       u16* __restrict__ meff, int b0, int total)
{
    int g = blockIdx.x * 256 + threadIdx.x;
    if (g >= total) return;
    int b_l = g / 36864, rem = g % 36864;
    int o = rem / CD, c = rem % CD;
    int hh = c / 24, e = c % 24;
    int b = b0 + b_l;
    const float* Arow = attnS + ((size_t)b * 8 + hh) * 576;
    const float* Prow = projw + o * CD + hh * 24;
    float acc = 0.f;
    #pragma unroll
    for (int d = 0; d < 24; d++) acc += Prow[d] * Arow[d * 24 + e];
    meff[(size_t)b * 36864 + o * CD + c] = f2bf(acc);
}

// ---------------------------------------------------------------------------
// K5: out[b][o][p] = sum_c meff[b][o][c] * dwt[p][384+c]   (MFMA, fp32 out)
// ---------------------------------------------------------------------------
__launch_bounds__(256, 2)
__global__ void k_gemm2(const u16* __restrict__ A, const u16* __restrict__ X,
                        float* __restrict__ O)
{
    __shared__ __attribute__((aligned(16))) u16 As[192 * 40];
    __shared__ __attribute__((aligned(16))) u16 Xs[128 * 40];
    const int t    = threadIdx.x;
    const int pb   = blockIdx.z;
    const int p0   = blockIdx.x * 128;
    const int lane = t & 63, wid = t >> 6;
    const int quad = lane >> 4, l16 = lane & 15;
    const int wm0  = (wid >> 1) * 96, wn0 = (wid & 1) * 64;

    f32x4 acc[6][4];
    #pragma unroll
    for (int i = 0; i < 6; i++)
        #pragma unroll
        for (int j = 0; j < 4; j++) acc[i][j] = f32x4{0.f, 0.f, 0.f, 0.f};

    const u16* Ab = A + (size_t)36864 * pb;
    const u16* Xb = X + QB * pb;

    for (int kk = 0; kk < 6; kk++) {
        if (kk) __syncthreads();
        #pragma unroll
        for (int i = 0; i < 3; i++) {           // A tile: 192x32
            int s = t + i * 256;
            int m = s >> 2, part = s & 3;
            uint4 v = *(const uint4*)(Ab + (size_t)m * CD + kk * 32 + part * 8);
            *(uint4*)(&As[m * 40 + part * 8]) = v;
        }
        #pragma unroll
        for (int i = 0; i < 2; i++) {           // X tile: 128 p x 32 c (v cols)
            int s = t + i * 256;
            int p = s >> 2, part = s & 3;
            uint4 v = *(const uint4*)(Xb + (size_t)(p0 + p) * C3 + 384 + kk * 32 + part * 8);
            *(uint4*)(&Xs[p * 40 + part * 8]) = v;
        }
        __syncthreads();
        s16x8 af[6], bfr[4];
        #pragma unroll
        for (int i = 0; i < 6; i++)
            af[i] = *(const s16x8*)(&As[(wm0 + i * 16 + l16) * 40 + quad * 8]);
        #pragma unroll
        for (int j = 0; j < 4; j++)
            bfr[j] = *(const s16x8*)(&Xs[(wn0 + j * 16 + l16) * 40 + quad * 8]);
        #pragma unroll
        for (int i = 0; i < 6; i++)
            #pragma unroll
            for (int j = 0; j < 4; j++)
                acc[i][j] = __builtin_amdgcn_mfma_f32_16x16x32_bf16(af[i], bfr[j], acc[i][j], 0, 0, 0);
    }

    float* Ob = O + (size_t)CD * HW * pb;
    #pragma unroll
    for (int i = 0; i < 6; i++) {
        const int o = wm0 + i * 16 + quad * 4;
        #pragma unroll
        for (int j = 0; j < 4; j++) {
            const int p = p0 + wn0 + j * 16 + l16;
            #pragma unroll
            for (int r = 0; r < 4; r++)
                Ob[(size_t)(o + r) * HW + p] = acc[i][j][r];
        }
    }
}

// ---------------------------------------------------------------------------
extern "C" void kernel_launch(void* const* d_in, const int* in_sizes, int n_in,
                              void* d_out, int out_size, void* d_ws, size_t ws_size,
                              hipStream_t stream)
{
    (void)out_size;
    const float* x     = (const float*)d_in[0];
    const float* qkvw  = (const float*)d_in[1];
    const float* dww   = (const float*)d_in[2];
    const float* projw = (const float*)d_in[3];
    const float* temp  = (const float*)d_in[4];
    for (int i = 0; i < n_in; i++) {
        switch (in_sizes[i]) {
            case 50331648: x     = (const float*)d_in[i]; break;
            case 110592:   qkvw  = (const float*)d_in[i]; break;
            case 5184:     dww   = (const float*)d_in[i]; break;
            case 36864:    projw = (const float*)d_in[i]; break;
            case 8:        temp  = (const float*)d_in[i]; break;
            default: break;
        }
    }
    float* out = (float*)d_out;          // reference output dtype = float32
    char* ws = (char*)d_ws;

    const size_t sums_off  = 0;                      // 4*384*4    = 6144 B
    const size_t araw_off  = 6144;                   // 4*8*576*4  = 73728 B
    const size_t asmx_off  = araw_off + 73728;       // 73728 B
    const size_t meff_off  = asmx_off + 73728;       // 4*36864*2  = 294912 B (pad)
    const size_t qkvwb_off = meff_off + 294912;      // 576*192*2  = 221184 B
    const size_t big_off   = (qkvwb_off + 221184 + 255) & ~(size_t)255;

    int P = 4;   // batches per pass; shrink if workspace is small
    while (P > 1 && big_off + (size_t)P * 2 * QB * 2 > ws_size) P >>= 1;

    float* sums  = (float*)(ws + sums_off);
    float* araw  = (float*)(ws + araw_off);
    float* attnS = (float*)(ws + asmx_off);
    u16*   meff  = (u16*)(ws + meff_off);
    u16*   qkvwb = (u16*)(ws + qkvwb_off);
    u16*   qkvt  = (u16*)(ws + big_off);
    u16*   dwt   = qkvt + (size_t)P * QB;

    hipMemsetAsync(ws + sums_off, 0, araw_off + 73728, stream);  // zero sums+araw
    k_convert<<<dim3(108), 256, 0, stream>>>(qkvw, qkvwb, 110592 / 4);

    for (int b0 = 0; b0 < 4; b0 += P) {
        k_qkv<<<dim3(512, 3, P), 256, 0, stream>>>(qkvwb, x, qkvt, b0);
        k_dw<<<dim3(32, 256, P), 256, 0, stream>>>(qkvt, dww, dwt);
        k_sumsq<<<dim3(128, P), 256, 0, stream>>>(dwt, sums, b0);
        k_attn<<<dim3(256, 8, P), 256, 0, stream>>>(dwt, araw, b0);
        k_softmax<<<dim3(8, P), 64, 0, stream>>>(araw, sums, temp, attnS, b0);
        k_meff<<<dim3(P * 144), 256, 0, stream>>>(attnS, projw, meff, b0, P * 36864);
        k_gemm2<<<dim3(512, 1, P), 256, 0, stream>>>(
            meff + (size_t)b0 * 36864, dwt, out + (size_t)b0 * CD * HW);
    }
}